// Round 2
// baseline (3487.330 us; speedup 1.0000x reference)
//
#include <hip/hip_runtime.h>
#include <hip/hip_bf16.h>
#include <stdint.h>
#include <stdio.h>

#define L_SEQ 8192
#define DIM_ 2048
#define HK_ 16
#define HV_ 32
#define DK_ 128
#define DV_ 128
#define CONV_DIM_ 8192
#define EPS_F 1e-6f

typedef __bf16 bf16;
typedef __bf16 bf16x8 __attribute__((ext_vector_type(8)));
typedef __bf16 bf16x4 __attribute__((ext_vector_type(4)));
typedef __bf16 bf16x2 __attribute__((ext_vector_type(2)));
typedef float f32x4 __attribute__((ext_vector_type(4)));

// ---------------------------------------------------------------- helpers
__device__ __forceinline__ void load_lds16(const void* g, void* l) {
  __builtin_amdgcn_global_load_lds((const __attribute__((address_space(1))) uint32_t*)g,
                                   (__attribute__((address_space(3))) uint32_t*)l,
                                   16, 0, 0);
}

// ---------------------------------------------------------------- fp32 -> bf16 convert (x)
__global__ __launch_bounds__(256) void k_convert(const float4* __restrict__ src,
                                                 bf16x4* __restrict__ dst, int n4) {
  int i = blockIdx.x * 256 + threadIdx.x;
  if (i >= n4) return;
  float4 v = src[i];
  bf16x4 o;
  o[0] = (bf16)v.x; o[1] = (bf16)v.y; o[2] = (bf16)v.z; o[3] = (bf16)v.w;
  dst[i] = o;
}

// ---------------------------------------------------------------- W [K][ldW] fp32 (cols n_off..n_off+Nout) -> Wt [Nout][K] bf16
__global__ __launch_bounds__(256) void k_transpose_cvt(const float* __restrict__ W,
                                                       bf16* __restrict__ Wt, int K, int ldW,
                                                       int n_off) {
  __shared__ float tile[32][33];
  int n0 = blockIdx.x * 32, k0 = blockIdx.y * 32;
  int cx = threadIdx.x & 31, ry = threadIdx.x >> 5;  // ry in 0..7
#pragma unroll
  for (int i = 0; i < 4; i++)
    tile[ry + i * 8][cx] = W[(size_t)(k0 + ry + i * 8) * ldW + n_off + n0 + cx];
  __syncthreads();
#pragma unroll
  for (int i = 0; i < 4; i++) {
    int r = ry + i * 8;
    Wt[(size_t)(n0 + r) * K + k0 + cx] = (bf16)tile[cx][r];
  }
}

// ---------------------------------------------------------------- bf16 MFMA GEMM: C[M,N] = A[M,K] @ Bt[N,K]^T
template <int BF16_OUT>
__global__ __launch_bounds__(256) void k_gemm_bt(const bf16* __restrict__ A,
                                                 const bf16* __restrict__ Bt,
                                                 void* __restrict__ Cout,
                                                 int M, int N, int K) {
  __shared__ __align__(16) bf16 la[4096];  // [kchunk 4][row 128][8]
  __shared__ __align__(16) bf16 lb[4096];
  const int tid = threadIdx.x;
  const int lane = tid & 63;
  const int wave = tid >> 6;
  const int wm = wave >> 1, wn = wave & 1;
  const int bm = blockIdx.y << 7, bn = blockIdx.x << 7;

  f32x4 acc[4][4];
#pragma unroll
  for (int i = 0; i < 4; i++)
#pragma unroll
    for (int j = 0; j < 4; j++) acc[i][j] = (f32x4){0.f, 0.f, 0.f, 0.f};

  const bf16* Ag = A + (size_t)(bm + lane) * K + wave * 8;
  const bf16* Bg = Bt + (size_t)(bn + lane) * K + wave * 8;
  bf16* lA = la + wave * 1024;
  bf16* lB = lb + wave * 1024;
  const size_t rowskip = (size_t)64 * K;

  const int chunk = lane >> 4;
  const int rr = lane & 15;
  const bf16* fa = la + chunk * 1024 + (wm * 64 + rr) * 8;
  const bf16* fb = lb + chunk * 1024 + (wn * 64 + rr) * 8;

  for (int k0 = 0; k0 < K; k0 += 32) {
    __syncthreads();
    load_lds16(Ag + k0, lA);
    load_lds16(Ag + k0 + rowskip, lA + 512);
    load_lds16(Bg + k0, lB);
    load_lds16(Bg + k0 + rowskip, lB + 512);
    __syncthreads();
    bf16x8 af[4], bfr[4];
#pragma unroll
    for (int i = 0; i < 4; i++) {
      af[i] = *(const bf16x8*)(fa + i * 16 * 8);
      bfr[i] = *(const bf16x8*)(fb + i * 16 * 8);
    }
#pragma unroll
    for (int mi = 0; mi < 4; mi++)
#pragma unroll
      for (int ni = 0; ni < 4; ni++)
        acc[mi][ni] = __builtin_amdgcn_mfma_f32_16x16x32_bf16(af[mi], bfr[ni], acc[mi][ni], 0, 0, 0);
  }

  const int col = bn + wn * 64 + rr;
  const int row0 = bm + wm * 64 + (lane >> 4) * 4;
#pragma unroll
  for (int mi = 0; mi < 4; mi++)
#pragma unroll
    for (int ni = 0; ni < 4; ni++)
#pragma unroll
      for (int r = 0; r < 4; r++) {
        int rowi = row0 + mi * 16 + r;
        int coli = col + ni * 16;
        if (BF16_OUT)
          ((bf16*)Cout)[(size_t)rowi * N + coli] = (bf16)acc[mi][ni][r];
        else
          ((float*)Cout)[(size_t)rowi * N + coli] = acc[mi][ni][r];
      }
}

// ---------------------------------------------------------------- gates: a,b GEMV + gamma/beta
// gb layout: [t][0..31]=gamma, [t][32..63]=beta
__global__ __launch_bounds__(256) void k_gates(const float* __restrict__ x,
                                               const float* __restrict__ Wa,
                                               const float* __restrict__ Wb,
                                               const float* __restrict__ A_log,
                                               const float* __restrict__ dt_bias,
                                               float* __restrict__ gb) {
  int t = blockIdx.x * 4 + (threadIdx.x >> 6);
  int lane = threadIdx.x & 63;
  int h = lane & 31;
  int isB = lane >> 5;
  const float* W = isB ? Wb : Wa;
  const float* xr = x + (size_t)t * DIM_;
  float a0 = 0.f, a1 = 0.f, a2 = 0.f, a3 = 0.f;
  for (int kk = 0; kk < DIM_; kk += 4) {
    float4 xv = *(const float4*)(xr + kk);
    a0 += xv.x * W[(kk + 0) * 32 + h];
    a1 += xv.y * W[(kk + 1) * 32 + h];
    a2 += xv.z * W[(kk + 2) * 32 + h];
    a3 += xv.w * W[(kk + 3) * 32 + h];
  }
  float acc = (a0 + a1) + (a2 + a3);
  if (isB) {
    gb[(size_t)t * 64 + 32 + h] = 1.f / (1.f + expf(-acc));
  } else {
    float ag = acc + dt_bias[h];
    float sp = (ag > 20.f) ? ag : log1pf(expf(ag));
    gb[(size_t)t * 64 + h] = expf(-expf(A_log[h]) * sp);
  }
}

// ---------------------------------------------------------------- conv + silu (+ l2norm for q/k)
// src: [L][4096] bf16 (qk half: channels grp*128+i; v half: channels 4096+grp*128+i)
// is_v==0: grp 0..15 -> qn head grp, grp 16..31 -> kn head grp-16 (both l2-normed, q scaled)
// is_v==1: grp 0..31 -> v head grp (no norm)
template <int IS_V>
__global__ __launch_bounds__(128) void k_conv(const bf16* __restrict__ src,
                                              const float* __restrict__ conv_w,
                                              const int* __restrict__ cu, int nseq,
                                              bf16* __restrict__ qn, bf16* __restrict__ kn,
                                              bf16* __restrict__ v) {
  __shared__ float red[2];
  int t = blockIdx.x;
  int grp = blockIdx.y;  // 0..31
  int c = grp * 128 + threadIdx.x;  // column within this half
  int start = 0;
  for (int s = 0; s < nseq; s++) {
    int a = cu[s];
    if (a <= t) start = a;
  }
  float4 w = *(const float4*)(conv_w + (size_t)(c + (IS_V ? 4096 : 0)) * 4);
  float accv = 0.f;
#pragma unroll
  for (int i = 0; i < 4; i++) {
    int tp = t - 3 + i;
    if (tp >= start) {
      float wv = (i == 0) ? w.x : (i == 1) ? w.y : (i == 2) ? w.z : w.w;
      accv += wv * (float)src[(size_t)tp * 4096 + c];
    }
  }
  float val = accv / (1.f + __expf(-accv));  // silu
  if (IS_V) {
    v[((size_t)t * HV_ + grp) * DV_ + threadIdx.x] = (bf16)val;
  } else {
    float ss = val * val;
#pragma unroll
    for (int off = 1; off < 64; off <<= 1) ss += __shfl_xor(ss, off);
    if ((threadIdx.x & 63) == 0) red[threadIdx.x >> 6] = ss;
    __syncthreads();
    float tot = red[0] + red[1];
    float scale = rsqrtf(tot + EPS_F);
    if (grp < 16) {
      scale *= 0.08838834764831845f;  // DK^-0.5
      qn[((size_t)t * HK_ + grp) * DK_ + threadIdx.x] = (bf16)(val * scale);
    } else {
      kn[((size_t)t * HK_ + (grp - 16)) * DK_ + threadIdx.x] = (bf16)(val * scale);
    }
  }
}

// ---------------------------------------------------------------- sequential gated delta scan
__device__ __forceinline__ void load16bf(float* dst, const bf16* src) {
  bf16x8 a = *(const bf16x8*)src;
  bf16x8 b = *(const bf16x8*)(src + 8);
#pragma unroll
  for (int j = 0; j < 8; j++) {
    dst[j] = (float)a[j];
    dst[8 + j] = (float)b[j];
  }
}

__device__ __forceinline__ void scan_step(float* S, const float* kf, const float* qf,
                                          float vv, float ga, float be, int qt, bf16* op) {
  float p0 = 0.f, p1 = 0.f, p2 = 0.f, p3 = 0.f;
#pragma unroll
  for (int j = 0; j < 4; j++) {
    p0 += kf[j] * S[j];
    p1 += kf[4 + j] * S[4 + j];
    p2 += kf[8 + j] * S[8 + j];
    p3 += kf[12 + j] * S[12 + j];
  }
  float pk = (p0 + p1) + (p2 + p3);
  pk += __shfl_xor(pk, 1);
  pk += __shfl_xor(pk, 2);
  pk += __shfl_xor(pk, 4);
  float delta = (vv - ga * pk) * be;
  float o0 = 0.f, o1 = 0.f, o2 = 0.f, o3 = 0.f;
#pragma unroll
  for (int j = 0; j < 4; j++) {
    S[j] = fmaf(ga, S[j], kf[j] * delta);             o0 += qf[j] * S[j];
    S[4 + j] = fmaf(ga, S[4 + j], kf[4 + j] * delta); o1 += qf[4 + j] * S[4 + j];
    S[8 + j] = fmaf(ga, S[8 + j], kf[8 + j] * delta); o2 += qf[8 + j] * S[8 + j];
    S[12 + j] = fmaf(ga, S[12 + j], kf[12 + j] * delta); o3 += qf[12 + j] * S[12 + j];
  }
  float po = (o0 + o1) + (o2 + o3);
  po += __shfl_xor(po, 1);
  po += __shfl_xor(po, 2);
  po += __shfl_xor(po, 4);
  if (qt == 0) *op = (bf16)po;
}

__global__ __launch_bounds__(256) void k_scan(const bf16* __restrict__ qn,
                                              const bf16* __restrict__ kn,
                                              const bf16* __restrict__ v,
                                              const float* __restrict__ gb,
                                              const int* __restrict__ cu,
                                              bf16* __restrict__ o) {
  const int h = blockIdx.y;
  const int hk = h >> 1;
  const int seq = blockIdx.z;
  const int dvb = blockIdx.x;            // 0..3
  const int c = threadIdx.x >> 3;        // 0..31
  const int qt = threadIdx.x & 7;        // 0..7, 16 dk each
  const int dv = dvb * 32 + c;
  int t0 = cu[seq], t1 = cu[seq + 1];
  if (t0 >= t1) return;

  const size_t KSTR = (size_t)HK_ * DK_;
  const size_t VSTR = (size_t)HV_ * DV_;

  float S[16];
#pragma unroll
  for (int j = 0; j < 16; j++) S[j] = 0.f;

  const bf16* kp = kn + ((size_t)t0 * HK_ + hk) * DK_ + qt * 16;
  const bf16* qp = qn + ((size_t)t0 * HK_ + hk) * DK_ + qt * 16;
  const bf16* vp = v + ((size_t)t0 * HV_ + h) * DV_ + dv;
  const float* gp = gb + (size_t)t0 * 64;
  bf16* op = o + ((size_t)t0 * HV_ + h) * DV_ + dv;

  float kf[16], qf[16], vv, ga, be;
  load16bf(kf, kp); load16bf(qf, qp);
  vv = (float)*vp; ga = gp[h]; be = gp[32 + h];

  int t = t0;
  while (t < t1) {
    float kf2[16], qf2[16], vv2 = 0.f, ga2 = 0.f, be2 = 0.f;
    bool more = (t + 1) < t1;
    if (more) {
      kp += KSTR; qp += KSTR; vp += VSTR; gp += 64;
      load16bf(kf2, kp); load16bf(qf2, qp);
      vv2 = (float)*vp; ga2 = gp[h]; be2 = gp[32 + h];
    }
    scan_step(S, kf, qf, vv, ga, be, qt, op);
    op += VSTR; t++;
    if (!more) break;
    bool more2 = (t + 1) < t1;
    if (more2) {
      kp += KSTR; qp += KSTR; vp += VSTR; gp += 64;
      load16bf(kf, kp); load16bf(qf, qp);
      vv = (float)*vp; ga = gp[h]; be = gp[32 + h];
    }
    scan_step(S, kf2, qf2, vv2, ga2, be2, qt, op);
    op += VSTR; t++;
  }
}

// ---------------------------------------------------------------- gated RMSNorm: y = norm(o*silu(z))*w (bf16, in place over z)
__global__ __launch_bounds__(256) void k_gatenorm(const bf16* __restrict__ o,
                                                  const bf16* __restrict__ z,
                                                  const float* __restrict__ norm_w,
                                                  bf16* __restrict__ y) {
  int row = blockIdx.x * 4 + (threadIdx.x >> 6);  // row = t*32 + h
  int lane = threadIdx.x & 63;
  int i0 = lane * 2;
  bf16x2 ov = *(const bf16x2*)(o + (size_t)row * 128 + i0);
  bf16x2 zv = *(const bf16x2*)(z + (size_t)row * 128 + i0);
  float zf0 = (float)zv[0], zf1 = (float)zv[1];
  float y0 = (float)ov[0] * (zf0 / (1.f + __expf(-zf0)));
  float y1 = (float)ov[1] * (zf1 / (1.f + __expf(-zf1)));
  float ss = y0 * y0 + y1 * y1;
#pragma unroll
  for (int off = 1; off < 64; off <<= 1) ss += __shfl_xor(ss, off);
  float scale = rsqrtf(ss * (1.f / 128.f) + EPS_F);
  float2 nw = *(const float2*)(norm_w + i0);
  bf16x2 out;
  out[0] = (bf16)(y0 * scale * nw.x);
  out[1] = (bf16)(y1 * scale * nw.y);
  *(bf16x2*)(y + (size_t)row * 128 + i0) = out;
}

// ---------------------------------------------------------------- launch
extern "C" void kernel_launch(void* const* d_in, const int* in_sizes, int n_in,
                              void* d_out, int out_size, void* d_ws, size_t ws_size,
                              hipStream_t stream) {
  const float* x = (const float*)d_in[0];
  const int* cu = (const int*)d_in[1];
  const float* Wqkv = (const float*)d_in[2];
  const float* Wz = (const float*)d_in[3];
  const float* Wa = (const float*)d_in[4];
  const float* Wb = (const float*)d_in[5];
  const float* conv_w = (const float*)d_in[6];
  const float* A_log = (const float*)d_in[7];
  const float* dt_bias = (const float*)d_in[8];
  const float* norm_w = (const float*)d_in[9];
  const float* Wout = (const float*)d_in[10];
  float* out = (float*)d_out;
  const int nseq = in_sizes[1] - 1;

  // ---- workspace layout (bytes), total 242 MiB of the 256 MiB budget ----
  const size_t MB = 1024 * 1024;
  char* ws = (char*)d_ws;
  bf16* x16   = (bf16*)(ws + 0);          // 32 MiB  [0,32)
  bf16* WtS   = (bf16*)(ws + 32 * MB);    // 16 MiB  [32,48)  transpose slot (reused 4x)
  bf16* qn    = (bf16*)(ws + 48 * MB);    // 32 MiB  [48,80)
  bf16* kn    = (bf16*)(ws + 80 * MB);    // 32 MiB  [80,112)
  bf16* bigA  = (bf16*)(ws + 112 * MB);   // 64 MiB  [112,176) qk-conv-in -> v-conv-in -> o
  bf16* vbuf  = (bf16*)(ws + 176 * MB);   // 64 MiB  [176,240)
  float* gb   = (float*)(ws + 240 * MB);  // 2 MiB   [240,242)
  bf16* z16   = qn;                       // 64 MiB overlay [48,112) (qn+kn dead after scan)
  bf16* o16   = bigA;
  bf16* y16   = z16;

  if (242 * MB > ws_size) {
    fprintf(stderr, "WORKSPACE TOO SMALL: need %zu, have %zu\n", 242 * MB, ws_size);
    return;
  }

  // 1. x -> bf16
  k_convert<<<(L_SEQ * DIM_ / 4 + 255) / 256, 256, 0, stream>>>((const float4*)x, (bf16x4*)x16,
                                                                L_SEQ * DIM_ / 4);
  // 2. gates (independent, reads fp32 x)
  k_gates<<<L_SEQ / 4, 256, 0, stream>>>(x, Wa, Wb, A_log, dt_bias, gb);

  // 3. qk half: transpose, GEMM, conv
  k_transpose_cvt<<<dim3(4096 / 32, DIM_ / 32), 256, 0, stream>>>(Wqkv, WtS, DIM_, CONV_DIM_, 0);
  k_gemm_bt<1><<<dim3(4096 / 128, L_SEQ / 128), 256, 0, stream>>>(x16, WtS, bigA, L_SEQ, 4096, DIM_);
  k_conv<0><<<dim3(L_SEQ, 32), 128, 0, stream>>>(bigA, conv_w, cu, nseq, qn, kn, vbuf);

  // 4. v half: transpose, GEMM, conv
  k_transpose_cvt<<<dim3(4096 / 32, DIM_ / 32), 256, 0, stream>>>(Wqkv, WtS, DIM_, CONV_DIM_, 4096);
  k_gemm_bt<1><<<dim3(4096 / 128, L_SEQ / 128), 256, 0, stream>>>(x16, WtS, bigA, L_SEQ, 4096, DIM_);
  k_conv<1><<<dim3(L_SEQ, 32), 128, 0, stream>>>(bigA, conv_w, cu, nseq, qn, kn, vbuf);

  // 5. scan -> o16 (overlays bigA, dead after conv_v)
  k_scan<<<dim3(4, HV_, nseq), 256, 0, stream>>>(qn, kn, vbuf, gb, cu, o16);

  // 6. z GEMM (overlays qn/kn, dead after scan)
  k_transpose_cvt<<<dim3(4096 / 32, DIM_ / 32), 256, 0, stream>>>(Wz, WtS, DIM_, 4096, 0);
  k_gemm_bt<1><<<dim3(4096 / 128, L_SEQ / 128), 256, 0, stream>>>(x16, WtS, z16, L_SEQ, 4096, DIM_);

  // 7. gated RMSNorm -> y16 (in place over z16)
  k_gatenorm<<<L_SEQ * HV_ / 4, 256, 0, stream>>>(o16, z16, norm_w, y16);

  // 8. out = y @ Wout
  k_transpose_cvt<<<dim3(DIM_ / 32, 4096 / 32), 256, 0, stream>>>(Wout, WtS, 4096, DIM_, 0);
  k_gemm_bt<0><<<dim3(DIM_ / 128, L_SEQ / 128), 256, 0, stream>>>(y16, WtS, out, L_SEQ, DIM_, 4096);
}

// Round 3
// 2985.666 us; speedup vs baseline: 1.1680x; 1.1680x over previous
//
#include <hip/hip_runtime.h>
#include <hip/hip_bf16.h>
#include <stdint.h>
#include <stdio.h>

#define L_SEQ 8192
#define DIM_ 2048
#define HK_ 16
#define HV_ 32
#define DK_ 128
#define DV_ 128
#define CONV_DIM_ 8192
#define EPS_F 1e-6f

typedef __bf16 bf16;
typedef __bf16 bf16x8 __attribute__((ext_vector_type(8)));
typedef __bf16 bf16x4 __attribute__((ext_vector_type(4)));
typedef __bf16 bf16x2 __attribute__((ext_vector_type(2)));
typedef float f32x4 __attribute__((ext_vector_type(4)));

// ---------------------------------------------------------------- helpers
__device__ __forceinline__ void load_lds16(const void* g, void* l) {
  __builtin_amdgcn_global_load_lds((const __attribute__((address_space(1))) uint32_t*)g,
                                   (__attribute__((address_space(3))) uint32_t*)l,
                                   16, 0, 0);
}
__device__ __forceinline__ void load_lds4(const void* g, void* l) {
  __builtin_amdgcn_global_load_lds((const __attribute__((address_space(1))) uint32_t*)g,
                                   (__attribute__((address_space(3))) uint32_t*)l,
                                   4, 0, 0);
}

// ---------------------------------------------------------------- fp32 -> bf16 convert (x)
__global__ __launch_bounds__(256) void k_convert(const float4* __restrict__ src,
                                                 bf16x4* __restrict__ dst, int n4) {
  int i = blockIdx.x * 256 + threadIdx.x;
  if (i >= n4) return;
  float4 v = src[i];
  bf16x4 o;
  o[0] = (bf16)v.x; o[1] = (bf16)v.y; o[2] = (bf16)v.z; o[3] = (bf16)v.w;
  dst[i] = o;
}

// ---------------------------------------------------------------- W [K][ldW] fp32 (cols n_off..n_off+Nout) -> Wt [Nout][K] bf16
__global__ __launch_bounds__(256) void k_transpose_cvt(const float* __restrict__ W,
                                                       bf16* __restrict__ Wt, int K, int ldW,
                                                       int n_off) {
  __shared__ float tile[32][33];
  int n0 = blockIdx.x * 32, k0 = blockIdx.y * 32;
  int cx = threadIdx.x & 31, ry = threadIdx.x >> 5;  // ry in 0..7
#pragma unroll
  for (int i = 0; i < 4; i++)
    tile[ry + i * 8][cx] = W[(size_t)(k0 + ry + i * 8) * ldW + n_off + n0 + cx];
  __syncthreads();
#pragma unroll
  for (int i = 0; i < 4; i++) {
    int r = ry + i * 8;
    Wt[(size_t)(n0 + r) * K + k0 + cx] = (bf16)tile[cx][r];
  }
}

// ---------------------------------------------------------------- bf16 MFMA GEMM: C[M,N] = A[M,K] @ Bt[N,K]^T
template <int BF16_OUT>
__global__ __launch_bounds__(256) void k_gemm_bt(const bf16* __restrict__ A,
                                                 const bf16* __restrict__ Bt,
                                                 void* __restrict__ Cout,
                                                 int M, int N, int K) {
  __shared__ __align__(16) bf16 la[4096];  // [kchunk 4][row 128][8]
  __shared__ __align__(16) bf16 lb[4096];
  const int tid = threadIdx.x;
  const int lane = tid & 63;
  const int wave = tid >> 6;
  const int wm = wave >> 1, wn = wave & 1;
  const int bm = blockIdx.y << 7, bn = blockIdx.x << 7;

  f32x4 acc[4][4];
#pragma unroll
  for (int i = 0; i < 4; i++)
#pragma unroll
    for (int j = 0; j < 4; j++) acc[i][j] = (f32x4){0.f, 0.f, 0.f, 0.f};

  const bf16* Ag = A + (size_t)(bm + lane) * K + wave * 8;
  const bf16* Bg = Bt + (size_t)(bn + lane) * K + wave * 8;
  bf16* lA = la + wave * 1024;
  bf16* lB = lb + wave * 1024;
  const size_t rowskip = (size_t)64 * K;

  const int chunk = lane >> 4;
  const int rr = lane & 15;
  const bf16* fa = la + chunk * 1024 + (wm * 64 + rr) * 8;
  const bf16* fb = lb + chunk * 1024 + (wn * 64 + rr) * 8;

  for (int k0 = 0; k0 < K; k0 += 32) {
    __syncthreads();
    load_lds16(Ag + k0, lA);
    load_lds16(Ag + k0 + rowskip, lA + 512);
    load_lds16(Bg + k0, lB);
    load_lds16(Bg + k0 + rowskip, lB + 512);
    __syncthreads();
    bf16x8 af[4], bfr[4];
#pragma unroll
    for (int i = 0; i < 4; i++) {
      af[i] = *(const bf16x8*)(fa + i * 16 * 8);
      bfr[i] = *(const bf16x8*)(fb + i * 16 * 8);
    }
#pragma unroll
    for (int mi = 0; mi < 4; mi++)
#pragma unroll
      for (int ni = 0; ni < 4; ni++)
        acc[mi][ni] = __builtin_amdgcn_mfma_f32_16x16x32_bf16(af[mi], bfr[ni], acc[mi][ni], 0, 0, 0);
  }

  const int col = bn + wn * 64 + rr;
  const int row0 = bm + wm * 64 + (lane >> 4) * 4;
#pragma unroll
  for (int mi = 0; mi < 4; mi++)
#pragma unroll
    for (int ni = 0; ni < 4; ni++)
#pragma unroll
      for (int r = 0; r < 4; r++) {
        int rowi = row0 + mi * 16 + r;
        int coli = col + ni * 16;
        if (BF16_OUT)
          ((bf16*)Cout)[(size_t)rowi * N + coli] = (bf16)acc[mi][ni][r];
        else
          ((float*)Cout)[(size_t)rowi * N + coli] = acc[mi][ni][r];
      }
}

// ---------------------------------------------------------------- gates: a,b GEMV + gamma/beta
// gb layout: [t][0..31]=gamma, [t][32..63]=beta
__global__ __launch_bounds__(256) void k_gates(const float* __restrict__ x,
                                               const float* __restrict__ Wa,
                                               const float* __restrict__ Wb,
                                               const float* __restrict__ A_log,
                                               const float* __restrict__ dt_bias,
                                               float* __restrict__ gb) {
  int t = blockIdx.x * 4 + (threadIdx.x >> 6);
  int lane = threadIdx.x & 63;
  int h = lane & 31;
  int isB = lane >> 5;
  const float* W = isB ? Wb : Wa;
  const float* xr = x + (size_t)t * DIM_;
  float a0 = 0.f, a1 = 0.f, a2 = 0.f, a3 = 0.f;
  for (int kk = 0; kk < DIM_; kk += 4) {
    float4 xv = *(const float4*)(xr + kk);
    a0 += xv.x * W[(kk + 0) * 32 + h];
    a1 += xv.y * W[(kk + 1) * 32 + h];
    a2 += xv.z * W[(kk + 2) * 32 + h];
    a3 += xv.w * W[(kk + 3) * 32 + h];
  }
  float acc = (a0 + a1) + (a2 + a3);
  if (isB) {
    gb[(size_t)t * 64 + 32 + h] = 1.f / (1.f + expf(-acc));
  } else {
    float ag = acc + dt_bias[h];
    float sp = (ag > 20.f) ? ag : log1pf(expf(ag));
    gb[(size_t)t * 64 + h] = expf(-expf(A_log[h]) * sp);
  }
}

// ---------------------------------------------------------------- conv + silu (+ l2norm for q/k)
template <int IS_V>
__global__ __launch_bounds__(128) void k_conv(const bf16* __restrict__ src,
                                              const float* __restrict__ conv_w,
                                              const int* __restrict__ cu, int nseq,
                                              bf16* __restrict__ qn, bf16* __restrict__ kn,
                                              bf16* __restrict__ v) {
  __shared__ float red[2];
  int t = blockIdx.x;
  int grp = blockIdx.y;  // 0..31
  int c = grp * 128 + threadIdx.x;  // column within this half
  int start = 0;
  for (int s = 0; s < nseq; s++) {
    int a = cu[s];
    if (a <= t) start = a;
  }
  float4 w = *(const float4*)(conv_w + (size_t)(c + (IS_V ? 4096 : 0)) * 4);
  float accv = 0.f;
#pragma unroll
  for (int i = 0; i < 4; i++) {
    int tp = t - 3 + i;
    if (tp >= start) {
      float wv = (i == 0) ? w.x : (i == 1) ? w.y : (i == 2) ? w.z : w.w;
      accv += wv * (float)src[(size_t)tp * 4096 + c];
    }
  }
  float val = accv / (1.f + __expf(-accv));  // silu
  if (IS_V) {
    v[((size_t)t * HV_ + grp) * DV_ + threadIdx.x] = (bf16)val;
  } else {
    float ss = val * val;
#pragma unroll
    for (int off = 1; off < 64; off <<= 1) ss += __shfl_xor(ss, off);
    if ((threadIdx.x & 63) == 0) red[threadIdx.x >> 6] = ss;
    __syncthreads();
    float tot = red[0] + red[1];
    float scale = rsqrtf(tot + EPS_F);
    if (grp < 16) {
      scale *= 0.08838834764831845f;  // DK^-0.5
      qn[((size_t)t * HK_ + grp) * DK_ + threadIdx.x] = (bf16)(val * scale);
    } else {
      kn[((size_t)t * HK_ + (grp - 16)) * DK_ + threadIdx.x] = (bf16)(val * scale);
    }
  }
}

// ---------------------------------------------------------------- sequential gated delta scan
// LDS-tiled: stage T_TILE=32 timesteps of k/q/v/gate via global_load_lds (double buffer),
// register-pipeline next step's LDS reads during current step's math.
#define T_TILE 32

__device__ __forceinline__ void unpack16(float* dst, bf16x8 a, bf16x8 b) {
#pragma unroll
  for (int j = 0; j < 8; j++) {
    dst[j] = (float)a[j];
    dst[8 + j] = (float)b[j];
  }
}

__device__ __forceinline__ float scan_step(float* S, const float* kf, const float* qf,
                                           float vv, float ga, float be) {
  float p0 = 0.f, p1 = 0.f, p2 = 0.f, p3 = 0.f;
#pragma unroll
  for (int j = 0; j < 4; j++) {
    p0 += kf[j] * S[j];
    p1 += kf[4 + j] * S[4 + j];
    p2 += kf[8 + j] * S[8 + j];
    p3 += kf[12 + j] * S[12 + j];
  }
  float pk = (p0 + p1) + (p2 + p3);
  pk += __shfl_xor(pk, 1);
  pk += __shfl_xor(pk, 2);
  pk += __shfl_xor(pk, 4);
  float delta = (vv - ga * pk) * be;
  float o0 = 0.f, o1 = 0.f, o2 = 0.f, o3 = 0.f;
#pragma unroll
  for (int j = 0; j < 4; j++) {
    S[j] = fmaf(ga, S[j], kf[j] * delta);             o0 += qf[j] * S[j];
    S[4 + j] = fmaf(ga, S[4 + j], kf[4 + j] * delta); o1 += qf[4 + j] * S[4 + j];
    S[8 + j] = fmaf(ga, S[8 + j], kf[8 + j] * delta); o2 += qf[8 + j] * S[8 + j];
    S[12 + j] = fmaf(ga, S[12 + j], kf[12 + j] * delta); o3 += qf[12 + j] * S[12 + j];
  }
  float po = (o0 + o1) + (o2 + o3);
  po += __shfl_xor(po, 1);
  po += __shfl_xor(po, 2);
  po += __shfl_xor(po, 4);
  return po;
}

__global__ __launch_bounds__(256) void k_scan(const bf16* __restrict__ qn,
                                              const bf16* __restrict__ kn,
                                              const bf16* __restrict__ v,
                                              const float* __restrict__ gb,
                                              const int* __restrict__ cu,
                                              bf16* __restrict__ o) {
  __shared__ __align__(16) bf16 sk[2][T_TILE][128];
  __shared__ __align__(16) bf16 sq[2][T_TILE][128];
  __shared__ __align__(16) bf16 sv[2][T_TILE][32];
  __shared__ __align__(8) float sg[2][T_TILE][2];

  const int h = blockIdx.y;
  const int hk = h >> 1;
  const int seq = blockIdx.z;
  const int dvb = blockIdx.x;            // 0..3
  const int tid = threadIdx.x;
  const int c = tid >> 3;                // 0..31 (dv col within slice)
  const int qt = tid & 7;                // 0..7 (16 dk each)
  const int wave = tid >> 6;
  const int lane = tid & 63;
  const int dv = dvb * 32 + c;
  const int t0 = cu[seq], t1 = cu[seq + 1];
  if (t0 >= t1) return;

  float S[16];
#pragma unroll
  for (int j = 0; j < 16; j++) S[j] = 0.f;

  // ---- staging: one tile of T_TILE steps into buffer b ----
  auto stage = [&](int b, int ts) {
    // k,q: 2 rounds x (4 waves x 4 rows x 16B/lane)
#pragma unroll
    for (int round = 0; round < 2; round++) {
      int r = round * 16 + wave * 4 + (lane >> 4);
      int tr = ts + r; if (tr > t1 - 1) tr = t1 - 1;
      int col = (lane & 15) * 8;
      size_t goff = (size_t)tr * (HK_ * DK_) + hk * DK_ + col;
      load_lds16(kn + goff, &sk[b][0][0] + r * 128 + col);
      load_lds16(qn + goff, &sq[b][0][0] + r * 128 + col);
    }
    if (wave < 2) {  // v: 2 waves x 16 rows x (4 lanes x 16B)
      int r = wave * 16 + (lane >> 2);
      int tr = ts + r; if (tr > t1 - 1) tr = t1 - 1;
      int col = (lane & 3) * 8;
      load_lds16(v + (size_t)tr * (HV_ * DV_) + h * DV_ + dvb * 32 + col,
                 &sv[b][0][0] + r * 32 + col);
    } else if (wave == 2) {  // gamma/beta: 1 wave x 32 rows x 2 floats
      int r = lane >> 1;
      int tr = ts + r; if (tr > t1 - 1) tr = t1 - 1;
      int which = lane & 1;
      load_lds4(gb + (size_t)tr * 64 + which * 32 + h, &sg[b][0][0] + r * 2 + which);
    }
  };

  int buf = 0;
  stage(0, t0);
  __syncthreads();

  for (int ts = t0; ts < t1; ts += T_TILE) {
    const int len = min(T_TILE, t1 - ts);
    if (ts + T_TILE < t1) stage(buf ^ 1, ts + T_TILE);

    // register-pipelined inner loop over the tile
    bf16x8 ck0 = *(const bf16x8*)&sk[buf][0][qt * 16];
    bf16x8 ck1 = *(const bf16x8*)&sk[buf][0][qt * 16 + 8];
    bf16x8 cq0 = *(const bf16x8*)&sq[buf][0][qt * 16];
    bf16x8 cq1 = *(const bf16x8*)&sq[buf][0][qt * 16 + 8];
    float vv = (float)sv[buf][0][c];
    float2 gbe = *(const float2*)&sg[buf][0][0];

    bf16* op = o + ((size_t)ts * HV_ + h) * DV_ + dv;
#pragma unroll 2
    for (int j = 0; j < len; j++) {
      int jn = (j + 1 < len) ? j + 1 : j;
      bf16x8 nk0 = *(const bf16x8*)&sk[buf][jn][qt * 16];
      bf16x8 nk1 = *(const bf16x8*)&sk[buf][jn][qt * 16 + 8];
      bf16x8 nq0 = *(const bf16x8*)&sq[buf][jn][qt * 16];
      bf16x8 nq1 = *(const bf16x8*)&sq[buf][jn][qt * 16 + 8];
      float nvv = (float)sv[buf][jn][c];
      float2 ngbe = *(const float2*)&sg[buf][jn][0];

      float kf[16], qf[16];
      unpack16(kf, ck0, ck1);
      unpack16(qf, cq0, cq1);
      float po = scan_step(S, kf, qf, vv, gbe.x, gbe.y);
      if (qt == 0) *op = (bf16)po;
      op += HV_ * DV_;

      ck0 = nk0; ck1 = nk1; cq0 = nq0; cq1 = nq1; vv = nvv; gbe = ngbe;
    }
    __syncthreads();  // drains next-tile DMA (vmcnt) + all LDS reads of buf
    buf ^= 1;
  }
}

// ---------------------------------------------------------------- gated RMSNorm: y = norm(o*silu(z))*w (bf16, in place over z)
__global__ __launch_bounds__(256) void k_gatenorm(const bf16* __restrict__ o,
                                                  const bf16* __restrict__ z,
                                                  const float* __restrict__ norm_w,
                                                  bf16* __restrict__ y) {
  int row = blockIdx.x * 4 + (threadIdx.x >> 6);  // row = t*32 + h
  int lane = threadIdx.x & 63;
  int i0 = lane * 2;
  bf16x2 ov = *(const bf16x2*)(o + (size_t)row * 128 + i0);
  bf16x2 zv = *(const bf16x2*)(z + (size_t)row * 128 + i0);
  float zf0 = (float)zv[0], zf1 = (float)zv[1];
  float y0 = (float)ov[0] * (zf0 / (1.f + __expf(-zf0)));
  float y1 = (float)ov[1] * (zf1 / (1.f + __expf(-zf1)));
  float ss = y0 * y0 + y1 * y1;
#pragma unroll
  for (int off = 1; off < 64; off <<= 1) ss += __shfl_xor(ss, off);
  float scale = rsqrtf(ss * (1.f / 128.f) + EPS_F);
  float2 nw = *(const float2*)(norm_w + i0);
  bf16x2 out;
  out[0] = (bf16)(y0 * scale * nw.x);
  out[1] = (bf16)(y1 * scale * nw.y);
  *(bf16x2*)(y + (size_t)row * 128 + i0) = out;
}

// ---------------------------------------------------------------- launch
extern "C" void kernel_launch(void* const* d_in, const int* in_sizes, int n_in,
                              void* d_out, int out_size, void* d_ws, size_t ws_size,
                              hipStream_t stream) {
  const float* x = (const float*)d_in[0];
  const int* cu = (const int*)d_in[1];
  const float* Wqkv = (const float*)d_in[2];
  const float* Wz = (const float*)d_in[3];
  const float* Wa = (const float*)d_in[4];
  const float* Wb = (const float*)d_in[5];
  const float* conv_w = (const float*)d_in[6];
  const float* A_log = (const float*)d_in[7];
  const float* dt_bias = (const float*)d_in[8];
  const float* norm_w = (const float*)d_in[9];
  const float* Wout = (const float*)d_in[10];
  float* out = (float*)d_out;
  const int nseq = in_sizes[1] - 1;

  // ---- workspace layout (bytes), total 242 MiB of the 256 MiB budget ----
  const size_t MB = 1024 * 1024;
  char* ws = (char*)d_ws;
  bf16* x16   = (bf16*)(ws + 0);          // 32 MiB  [0,32)
  bf16* WtS   = (bf16*)(ws + 32 * MB);    // 16 MiB  [32,48)  transpose slot (reused 4x)
  bf16* qn    = (bf16*)(ws + 48 * MB);    // 32 MiB  [48,80)
  bf16* kn    = (bf16*)(ws + 80 * MB);    // 32 MiB  [80,112)
  bf16* bigA  = (bf16*)(ws + 112 * MB);   // 64 MiB  [112,176) qk-conv-in -> v-conv-in -> o
  bf16* vbuf  = (bf16*)(ws + 176 * MB);   // 64 MiB  [176,240)
  float* gb   = (float*)(ws + 240 * MB);  // 2 MiB   [240,242)
  bf16* z16   = qn;                       // 64 MiB overlay [48,112) (qn+kn dead after scan)
  bf16* o16   = bigA;
  bf16* y16   = z16;

  if (242 * MB > ws_size) {
    fprintf(stderr, "WORKSPACE TOO SMALL: need %zu, have %zu\n", 242 * MB, ws_size);
    return;
  }

  // 1. x -> bf16
  k_convert<<<(L_SEQ * DIM_ / 4 + 255) / 256, 256, 0, stream>>>((const float4*)x, (bf16x4*)x16,
                                                                L_SEQ * DIM_ / 4);
  // 2. gates (independent, reads fp32 x)
  k_gates<<<L_SEQ / 4, 256, 0, stream>>>(x, Wa, Wb, A_log, dt_bias, gb);

  // 3. qk half: transpose, GEMM, conv
  k_transpose_cvt<<<dim3(4096 / 32, DIM_ / 32), 256, 0, stream>>>(Wqkv, WtS, DIM_, CONV_DIM_, 0);
  k_gemm_bt<1><<<dim3(4096 / 128, L_SEQ / 128), 256, 0, stream>>>(x16, WtS, bigA, L_SEQ, 4096, DIM_);
  k_conv<0><<<dim3(L_SEQ, 32), 128, 0, stream>>>(bigA, conv_w, cu, nseq, qn, kn, vbuf);

  // 4. v half: transpose, GEMM, conv
  k_transpose_cvt<<<dim3(4096 / 32, DIM_ / 32), 256, 0, stream>>>(Wqkv, WtS, DIM_, CONV_DIM_, 4096);
  k_gemm_bt<1><<<dim3(4096 / 128, L_SEQ / 128), 256, 0, stream>>>(x16, WtS, bigA, L_SEQ, 4096, DIM_);
  k_conv<1><<<dim3(L_SEQ, 32), 128, 0, stream>>>(bigA, conv_w, cu, nseq, qn, kn, vbuf);

  // 5. scan -> o16 (overlays bigA, dead after conv_v)
  k_scan<<<dim3(4, HV_, nseq), 256, 0, stream>>>(qn, kn, vbuf, gb, cu, o16);

  // 6. z GEMM (overlays qn/kn, dead after scan)
  k_transpose_cvt<<<dim3(4096 / 32, DIM_ / 32), 256, 0, stream>>>(Wz, WtS, DIM_, 4096, 0);
  k_gemm_bt<1><<<dim3(4096 / 128, L_SEQ / 128), 256, 0, stream>>>(x16, WtS, z16, L_SEQ, 4096, DIM_);

  // 7. gated RMSNorm -> y16 (in place over z16)
  k_gatenorm<<<L_SEQ * HV_ / 4, 256, 0, stream>>>(o16, z16, norm_w, y16);

  // 8. out = y @ Wout
  k_transpose_cvt<<<dim3(DIM_ / 32, 4096 / 32), 256, 0, stream>>>(Wout, WtS, 4096, DIM_, 0);
  k_gemm_bt<0><<<dim3(DIM_ / 128, L_SEQ / 128), 256, 0, stream>>>(y16, WtS, out, L_SEQ, DIM_, 4096);
}